// Round 1
// baseline (557.171 us; speedup 1.0000x reference)
//
#include <hip/hip_runtime.h>
#include <math.h>

#define Bsz 4
#define Sq  2048
#define Eq  1024
#define Hh  16
#define DHd 64
#define Kb  9
#define GSTR 72  // gemm LDS row stride (halves)

typedef _Float16 f16;
typedef __attribute__((ext_vector_type(8))) _Float16 fh8;   // MFMA A/B frag (4 VGPRs)
typedef __attribute__((ext_vector_type(4))) _Float16 fh4;
typedef __attribute__((ext_vector_type(2))) _Float16 fh2;
typedef __attribute__((ext_vector_type(4))) float fx4;      // 16x16 C/D frag
typedef __attribute__((ext_vector_type(16))) float fx16;    // 32x32 C/D frag
typedef __attribute__((ext_vector_type(4))) int i4;

#define CE 2.71828182845904523536f  // exp(+1) mask factor

// ---------------------------------------------------------------------------
// passage id + column attrs.
//   pidr: raw pid (rows; <0 => query row)
//   pcs : sentineled pid for columns (-2 when out-of-passage)
//   ecv : exp(colval) column factor (colval = rel or 1.0)
// ---------------------------------------------------------------------------
__global__ void pid_kernel(const int* __restrict__ bnd, const float* __restrict__ rel,
                           int* __restrict__ pidr, int* __restrict__ pcs,
                           float* __restrict__ ecv) {
  int idx = blockIdx.x * blockDim.x + threadIdx.x;
  if (idx >= Bsz * Sq) return;
  int b = idx >> 11;
  int s = idx & (Sq - 1);
  int j = -1;
#pragma unroll
  for (int t = 0; t < Kb; ++t) {
    if (bnd[b * Kb + t] <= s) j = t;
  }
  pidr[idx] = j;
  bool inp = (j >= 0 && j < Kb - 1);
  pcs[idx] = inp ? j : -2;
  float cv = inp ? rel[b * (Kb - 1) + j] : 1.0f;
  ecv[idx] = __expf(cv);
}

// ---------------------------------------------------------------------------
// fp32 -> fp16 cast, 8 elems/thread
// ---------------------------------------------------------------------------
__global__ __launch_bounds__(256) void cvt_hs(const float* __restrict__ x,
                                              f16* __restrict__ xo) {
  int i = (blockIdx.x * blockDim.x + threadIdx.x) * 8;
  float4 a = *(const float4*)&x[i];
  float4 b = *(const float4*)&x[i + 4];
  fh8 o;
  o[0] = (f16)a.x; o[1] = (f16)a.y; o[2] = (f16)a.z; o[3] = (f16)a.w;
  o[4] = (f16)b.x; o[5] = (f16)b.y; o[6] = (f16)b.z; o[7] = (f16)b.w;
  *(fh8*)&xo[i] = o;
}

// ---------------------------------------------------------------------------
// fp16 MFMA GEMM: C = A * B^T + bias  (unchanged structure from prev round)
// MODE 1: q is additionally scaled by 0.125*log2(e) so attn can use exp2f.
// ---------------------------------------------------------------------------
template <int MODE>
__global__ __launch_bounds__(256) void gemm_f16(
    const f16* __restrict__ A, const float* __restrict__ Bf,
    const float* __restrict__ bias, float* __restrict__ Cp,
    int M, int N, int Kd,
    f16* __restrict__ qo, f16* __restrict__ ko, f16* __restrict__ vto) {
  __shared__ __align__(16) f16 Ash[128 * GSTR];
  __shared__ __align__(16) f16 Bsh[128 * GSTR];

  const int tid = threadIdx.x;
  const int lane = tid & 63, w = tid >> 6;
  const int wm = w >> 1, wn = w & 1;
  const int q16 = lane & 15, quad = lane >> 4;
  const int m_blk = blockIdx.y * 128, n_blk = blockIdx.x * 128;

  fx4 acc[4][4];
#pragma unroll
  for (int mt = 0; mt < 4; ++mt)
#pragma unroll
    for (int nt = 0; nt < 4; ++nt)
#pragma unroll
      for (int r = 0; r < 4; ++r) acc[mt][nt][r] = 0.f;

  const int sr = tid >> 2, sc = (tid & 3) * 16;

  for (int k0 = 0; k0 < Kd; k0 += 64) {
    __syncthreads();
#pragma unroll
    for (int h = 0; h < 2; ++h) {
      const int r = sr + h * 64;
      const f16* ga = &A[(size_t)(m_blk + r) * Kd + k0 + sc];
      *(fh8*)&Ash[r * GSTR + sc]     = *(const fh8*)&ga[0];
      *(fh8*)&Ash[r * GSTR + sc + 8] = *(const fh8*)&ga[8];
      const float* gb = &Bf[(size_t)(n_blk + r) * Kd + k0 + sc];
      float4 f0 = *(const float4*)&gb[0];
      float4 f1 = *(const float4*)&gb[4];
      float4 f2 = *(const float4*)&gb[8];
      float4 f3 = *(const float4*)&gb[12];
      fh8 b0, b1;
      b0[0] = (f16)f0.x; b0[1] = (f16)f0.y; b0[2] = (f16)f0.z; b0[3] = (f16)f0.w;
      b0[4] = (f16)f1.x; b0[5] = (f16)f1.y; b0[6] = (f16)f1.z; b0[7] = (f16)f1.w;
      b1[0] = (f16)f2.x; b1[1] = (f16)f2.y; b1[2] = (f16)f2.z; b1[3] = (f16)f2.w;
      b1[4] = (f16)f3.x; b1[5] = (f16)f3.y; b1[6] = (f16)f3.z; b1[7] = (f16)f3.w;
      *(fh8*)&Bsh[r * GSTR + sc]     = b0;
      *(fh8*)&Bsh[r * GSTR + sc + 8] = b1;
    }
    __syncthreads();

#pragma unroll
    for (int ks = 0; ks < 2; ++ks) {
      fh8 af[4], bfr[4];
#pragma unroll
      for (int mt = 0; mt < 4; ++mt)
        af[mt] = *(const fh8*)&Ash[(wm * 64 + mt * 16 + q16) * GSTR + ks * 32 + quad * 8];
#pragma unroll
      for (int nt = 0; nt < 4; ++nt)
        bfr[nt] = *(const fh8*)&Bsh[(wn * 64 + nt * 16 + q16) * GSTR + ks * 32 + quad * 8];
#pragma unroll
      for (int nt = 0; nt < 4; ++nt)
#pragma unroll
        for (int mt = 0; mt < 4; ++mt)
          acc[mt][nt] = __builtin_amdgcn_mfma_f32_16x16x32_f16(af[mt], bfr[nt], acc[mt][nt], 0, 0, 0);
    }
  }

  float bsv[4];
#pragma unroll
  for (int nt = 0; nt < 4; ++nt) bsv[nt] = bias[n_blk + wn * 64 + nt * 16 + q16];

  if (MODE == 0) {
#pragma unroll
    for (int mt = 0; mt < 4; ++mt)
#pragma unroll
      for (int r = 0; r < 4; ++r) {
        int row = m_blk + wm * 64 + mt * 16 + quad * 4 + r;
#pragma unroll
        for (int nt = 0; nt < 4; ++nt) {
          int col = n_blk + wn * 64 + nt * 16 + q16;
          Cp[(size_t)row * N + col] = acc[mt][nt][r] + bsv[nt];
        }
      }
  } else {
    const int n0 = n_blk + wn * 64;
    const int which = n0 >> 10;
    const int hd = (n0 & 1023) >> 6;
    // q scale folds softmax 1/sqrt(DH)=0.125 AND log2(e) for exp2f-based softmax
    const float scale = (which == 0) ? 0.125f * 1.44269504088896340736f : 1.0f;
#pragma unroll
    for (int mt = 0; mt < 4; ++mt)
#pragma unroll
      for (int r = 0; r < 4; ++r) {
        int m = m_blk + wm * 64 + mt * 16 + quad * 4 + r;
        int b = m >> 11, s = m & (Sq - 1);
#pragma unroll
        for (int nt = 0; nt < 4; ++nt) {
          int d = nt * 16 + q16;
          float x = (acc[mt][nt][r] + bsv[nt]) * scale;
          if (which == 2) {  // V transposed: (B,H,DH,S)
            vto[(((size_t)(b * Hh + hd)) * DHd + d) * Sq + s] = (f16)x;
          } else {
            f16* dst = (which == 0) ? qo : ko;
            dst[(((size_t)(b * Hh + hd)) * Sq + s) * DHd + d] = (f16)x;
          }
        }
      }
  }
}

// ---------------------------------------------------------------------------
// Flash attention v2: swapped-QK 32x32 MFMA, P entirely in registers.
//   - S^T = mfma(K_frag, Q_frag): C col = q = lane&31 (one q-row per lane),
//     C row = key = (reg&3) + 8*(reg>>2) + 4*hi  (hi = lane>>5).
//   - Mask+exp lane-local (rq is per-lane scalar); exp2f (log2e folded into q).
//   - P -> PV B-frag via pack-f16-pairs + permlane32_swap (no LDS, no barriers).
//   - Row sums via ones-row MFMA (consistent f16 denominator).
//   - O^T = mfma(V^T_frag, P_frag): C row = d, col = q -> lane owns its q row.
// ---------------------------------------------------------------------------
__global__ __launch_bounds__(256, 2) void attn_v2(
    const f16* __restrict__ Qf, const f16* __restrict__ Kf,
    const f16* __restrict__ Vt, const int* __restrict__ pidr,
    const int* __restrict__ pcs, const float* __restrict__ ecv,
    f16* __restrict__ attf) {
  const int qb = blockIdx.x, hd = blockIdx.y, b = blockIdx.z;
  const int bh = b * Hh + hd;
  const int tid = threadIdx.x;
  const int lane = tid & 63, w = tid >> 6;
  const int l31 = lane & 31, hi = lane >> 5;

  const size_t qkbase = (size_t)bh * Sq * DHd;   // (b,h,s,d)
  const size_t vtbase = (size_t)bh * DHd * Sq;   // (b,h,d,s)
  const int qrow = qb * 128 + w * 32 + l31;

  // Q B-frags for whole sweep: B[col=q=l31][k = ds*16 + hi*8 + j]
  fh8 qf[4];
  {
    const f16* qp = &Qf[qkbase + (size_t)qrow * DHd + hi * 8];
#pragma unroll
    for (int ds = 0; ds < 4; ++ds) qf[ds] = *(const fh8*)&qp[ds * 16];
  }

  const int rq = pidr[b * Sq + qrow];
  const bool isq = (rq < 0);

  // ones A-frag: A[row=l31][k]=1 iff row 0 -> C row0 = per-q row sums
  fh8 onesf;
#pragma unroll
  for (int j = 0; j < 8; ++j) onesf[j] = (l31 == 0) ? (f16)1.0f : (f16)0.0f;

  fx16 o_acc[2], lacc;
#pragma unroll
  for (int r = 0; r < 16; ++r) { o_acc[0][r] = 0.f; o_acc[1][r] = 0.f; lacc[r] = 0.f; }

  // prefetch K A-frags for kt=0: A[row=key=l31][k = ds*16 + hi*8 + j]
  fh8 kf[4];
  {
    const f16* kp = &Kf[qkbase + (size_t)l31 * DHd + hi * 8];
#pragma unroll
    for (int ds = 0; ds < 4; ++ds) kf[ds] = *(const fh8*)&kp[ds * 16];
  }

  for (int kt = 0; kt < Sq / 32; ++kt) {
    // V^T A-frags: A[row=d = dt*32+l31][k = key = kb*16 + hi*8 + j]
    fh8 vf[2][2];
#pragma unroll
    for (int dt = 0; dt < 2; ++dt)
#pragma unroll
      for (int kb = 0; kb < 2; ++kb)
        vf[dt][kb] = *(const fh8*)&Vt[vtbase + (size_t)(dt * 32 + l31) * Sq +
                                      kt * 32 + kb * 16 + hi * 8];

    // column attrs; flat index r matches key = kt*32 + (r&3) + 8*(r>>2) + 4*hi
    float ec[16]; int pc[16];
    {
      const int cb = b * Sq + kt * 32 + 4 * hi;
#pragma unroll
      for (int g = 0; g < 4; ++g) {
        float4 e4 = *(const float4*)&ecv[cb + 8 * g];
        i4 p4 = *(const i4*)&pcs[cb + 8 * g];
        ec[4 * g + 0] = e4.x; ec[4 * g + 1] = e4.y;
        ec[4 * g + 2] = e4.z; ec[4 * g + 3] = e4.w;
        pc[4 * g + 0] = p4[0]; pc[4 * g + 1] = p4[1];
        pc[4 * g + 2] = p4[2]; pc[4 * g + 3] = p4[3];
      }
    }

    // ---- QK (swapped): sacc[r] = S^T[key][q] ----
    fx16 sacc;
#pragma unroll
    for (int r = 0; r < 16; ++r) sacc[r] = 0.f;
#pragma unroll
    for (int ds = 0; ds < 4; ++ds)
      sacc = __builtin_amdgcn_mfma_f32_32x32x16_f16(kf[ds], qf[ds], sacc, 0, 0, 0);

    // prefetch next K tile while softmax runs
    if (kt + 1 < Sq / 32) {
      const f16* kp = &Kf[qkbase + (size_t)((kt + 1) * 32 + l31) * DHd + hi * 8];
#pragma unroll
      for (int ds = 0; ds < 4; ++ds) kf[ds] = *(const fh8*)&kp[ds * 16];
    }

    // ---- mask + exp, pack f16 pairs ----
    // p = exp2(s') * f,  s' = s*log2e (folded into q),  f = e^{mask}
    float p[16];
#pragma unroll
    for (int r = 0; r < 16; ++r) {
      float f = isq ? ec[r] : ((rq == pc[r]) ? CE : 1.0f);
      p[r] = exp2f(sacc[r]) * f;
    }
    int pk[8];
#pragma unroll
    for (int i = 0; i < 8; ++i) {
      fh2 h; h[0] = (f16)p[2 * i]; h[1] = (f16)p[2 * i + 1];
      pk[i] = __builtin_bit_cast(int, h);
    }

    // ---- assemble P B-frags (B[col=q][k=hi*8+j]) + ones/PV MFMAs ----
#pragma unroll
    for (int kb = 0; kb < 2; ++kb) {
      int a01 = pk[4 * kb + 0], a23 = pk[4 * kb + 1];
      int a45 = pk[4 * kb + 2], a67 = pk[4 * kb + 3];
      i4 t;
#if __has_builtin(__builtin_amdgcn_permlane32_swap)
      auto s0 = __builtin_amdgcn_permlane32_swap(a01, a45, false, false);
      auto s1 = __builtin_amdgcn_permlane32_swap(a23, a67, false, false);
      t[0] = s0[0]; t[1] = s1[0]; t[2] = s0[1]; t[3] = s1[1];
#else
      int x01 = __shfl_xor(a01, 32), x23 = __shfl_xor(a23, 32);
      int x45 = __shfl_xor(a45, 32), x67 = __shfl_xor(a67, 32);
      t[0] = hi ? x45 : a01; t[1] = hi ? x67 : a23;
      t[2] = hi ? a45 : x01; t[3] = hi ? a67 : x23;
#endif
      fh8 pf = __builtin_bit_cast(fh8, t);
      lacc = __builtin_amdgcn_mfma_f32_32x32x16_f16(onesf, pf, lacc, 0, 0, 0);
      o_acc[0] = __builtin_amdgcn_mfma_f32_32x32x16_f16(vf[0][kb], pf, o_acc[0], 0, 0, 0);
      o_acc[1] = __builtin_amdgcn_mfma_f32_32x32x16_f16(vf[1][kb], pf, o_acc[1], 0, 0, 0);
    }
  }

  // epilogue: row sum lives in C row 0 = (reg0, hi=0 lanes); broadcast by q
  float l = __shfl(lacc[0], l31);
  float inv = 1.0f / l;
  size_t obase = ((size_t)(b * Sq + qrow)) * Eq + hd * 64 + 4 * hi;
#pragma unroll
  for (int dt = 0; dt < 2; ++dt)
#pragma unroll
    for (int g = 0; g < 4; ++g) {
      fh4 o4;
#pragma unroll
      for (int j = 0; j < 4; ++j) o4[j] = (f16)(o_acc[dt][4 * g + j] * inv);
      *(fh4*)&attf[obase + dt * 32 + 8 * g] = o4;
    }
}

// ---------------------------------------------------------------------------
extern "C" void kernel_launch(void* const* d_in, const int* in_sizes, int n_in,
                              void* d_out, int out_size, void* d_ws, size_t ws_size,
                              hipStream_t stream) {
  const float* hs = (const float*)d_in[0];
  const float* rel = (const float*)d_in[1];
  const int* bnd = (const int*)d_in[2];
  const float* wi = (const float*)d_in[3];
  const float* bi = (const float*)d_in[4];
  const float* wo = (const float*)d_in[5];
  const float* bo = (const float*)d_in[6];
  float* out = (float*)d_out;

  const size_t NQ = (size_t)Bsz * Hh * Sq * DHd;  // 8,388,608 (== B*S*E)
  char* p = (char*)d_ws;
  f16* qf = (f16*)p;   p += NQ * 2;
  f16* kf = (f16*)p;   p += NQ * 2;
  f16* vt = (f16*)p;   p += NQ * 2;
  f16* hsf = (f16*)p;  p += NQ * 2;
  f16* attf = (f16*)p; p += NQ * 2;
  int* pidr = (int*)p; p += Bsz * Sq * 4;
  int* pcs = (int*)p;  p += Bsz * Sq * 4;
  float* ecv = (float*)p;

  hipLaunchKernelGGL(pid_kernel, dim3((Bsz * Sq + 255) / 256), dim3(256), 0, stream,
                     bnd, rel, pidr, pcs, ecv);
  hipLaunchKernelGGL(cvt_hs, dim3((int)(NQ / 8 / 256)), dim3(256), 0, stream,
                     hs, hsf);
  hipLaunchKernelGGL((gemm_f16<1>), dim3(24, 64), dim3(256), 0, stream,
                     hsf, wi, bi, (float*)nullptr, Bsz * Sq, 3 * Eq, Eq,
                     qf, kf, vt);
  hipLaunchKernelGGL(attn_v2, dim3(16, 16, 4), dim3(256), 0, stream,
                     qf, kf, vt, pidr, pcs, ecv, attf);
  hipLaunchKernelGGL((gemm_f16<0>), dim3(8, 64), dim3(256), 0, stream,
                     attf, wo, bo, out, Bsz * Sq, Eq, Eq,
                     nullptr, nullptr, nullptr);
}

// Round 2
// 396.157 us; speedup vs baseline: 1.4064x; 1.4064x over previous
//
#include <hip/hip_runtime.h>
#include <math.h>

#define Bsz 4
#define Sq  2048
#define Eq  1024
#define Hh  16
#define DHd 64
#define Kb  9
#define GSTR 72  // gemm LDS row stride (halves)
#define LOG2E 1.44269504088896340736f

typedef _Float16 f16;
typedef __attribute__((ext_vector_type(8))) _Float16 fh8;   // MFMA A/B frag (4 VGPRs)
typedef __attribute__((ext_vector_type(4))) _Float16 fh4;
typedef __attribute__((ext_vector_type(2))) _Float16 fh2;
typedef __attribute__((ext_vector_type(4))) float fx4;      // 16x16 C/D frag
typedef __attribute__((ext_vector_type(16))) float fx16;    // 32x32 C/D frag
typedef __attribute__((ext_vector_type(4))) int i4;

// LDS swizzle: 64-half rows (128 B) -> XOR row into 16B-chunk index.
// Reads of 32 consecutive rows at fixed col become bank-conflict-free.
#define SWZ(r, c) ((r) * 64 + ((c) ^ (((r) & 7) << 3)))

// ---------------------------------------------------------------------------
// passage id + packed column attr.
//   pidr : raw pid (rows; <0 => query row)
//   cattr: float = colval*log2e (query-row log-factor) with sentineled pid
//          (pid+2, or 0 if out-of-passage) packed in the low 4 mantissa bits.
// ---------------------------------------------------------------------------
__global__ void pid_kernel(const int* __restrict__ bnd, const float* __restrict__ rel,
                           int* __restrict__ pidr, float* __restrict__ cattr) {
  int idx = blockIdx.x * blockDim.x + threadIdx.x;
  if (idx >= Bsz * Sq) return;
  int b = idx >> 11;
  int s = idx & (Sq - 1);
  int j = -1;
#pragma unroll
  for (int t = 0; t < Kb; ++t) {
    if (bnd[b * Kb + t] <= s) j = t;
  }
  pidr[idx] = j;
  bool inp = (j >= 0 && j < Kb - 1);
  float cv = inp ? rel[b * (Kb - 1) + j] : 1.0f;
  float lf = cv * LOG2E;
  int bits = (__float_as_int(lf) & ~15) | (inp ? (j + 2) : 0);
  cattr[idx] = __int_as_float(bits);
}

// ---------------------------------------------------------------------------
// fp32 -> fp16 cast, 8 elems/thread
// ---------------------------------------------------------------------------
__global__ __launch_bounds__(256) void cvt_hs(const float* __restrict__ x,
                                              f16* __restrict__ xo) {
  int i = (blockIdx.x * blockDim.x + threadIdx.x) * 8;
  float4 a = *(const float4*)&x[i];
  float4 b = *(const float4*)&x[i + 4];
  fh8 o;
  o[0] = (f16)a.x; o[1] = (f16)a.y; o[2] = (f16)a.z; o[3] = (f16)a.w;
  o[4] = (f16)b.x; o[5] = (f16)b.y; o[6] = (f16)b.z; o[7] = (f16)b.w;
  *(fh8*)&xo[i] = o;
}

// ---------------------------------------------------------------------------
// fp16 MFMA GEMM: C = A * B^T + bias  (structure unchanged)
// MODE 1: q additionally scaled by 0.125*log2(e) so attn can use exp2.
// ---------------------------------------------------------------------------
template <int MODE>
__global__ __launch_bounds__(256) void gemm_f16(
    const f16* __restrict__ A, const float* __restrict__ Bf,
    const float* __restrict__ bias, float* __restrict__ Cp,
    int M, int N, int Kd,
    f16* __restrict__ qo, f16* __restrict__ ko, f16* __restrict__ vto) {
  __shared__ __align__(16) f16 Ash[128 * GSTR];
  __shared__ __align__(16) f16 Bsh[128 * GSTR];

  const int tid = threadIdx.x;
  const int lane = tid & 63, w = tid >> 6;
  const int wm = w >> 1, wn = w & 1;
  const int q16 = lane & 15, quad = lane >> 4;
  const int m_blk = blockIdx.y * 128, n_blk = blockIdx.x * 128;

  fx4 acc[4][4];
#pragma unroll
  for (int mt = 0; mt < 4; ++mt)
#pragma unroll
    for (int nt = 0; nt < 4; ++nt)
#pragma unroll
      for (int r = 0; r < 4; ++r) acc[mt][nt][r] = 0.f;

  const int sr = tid >> 2, sc = (tid & 3) * 16;

  for (int k0 = 0; k0 < Kd; k0 += 64) {
    __syncthreads();
#pragma unroll
    for (int h = 0; h < 2; ++h) {
      const int r = sr + h * 64;
      const f16* ga = &A[(size_t)(m_blk + r) * Kd + k0 + sc];
      *(fh8*)&Ash[r * GSTR + sc]     = *(const fh8*)&ga[0];
      *(fh8*)&Ash[r * GSTR + sc + 8] = *(const fh8*)&ga[8];
      const float* gb = &Bf[(size_t)(n_blk + r) * Kd + k0 + sc];
      float4 f0 = *(const float4*)&gb[0];
      float4 f1 = *(const float4*)&gb[4];
      float4 f2 = *(const float4*)&gb[8];
      float4 f3 = *(const float4*)&gb[12];
      fh8 b0, b1;
      b0[0] = (f16)f0.x; b0[1] = (f16)f0.y; b0[2] = (f16)f0.z; b0[3] = (f16)f0.w;
      b0[4] = (f16)f1.x; b0[5] = (f16)f1.y; b0[6] = (f16)f1.z; b0[7] = (f16)f1.w;
      b1[0] = (f16)f2.x; b1[1] = (f16)f2.y; b1[2] = (f16)f2.z; b1[3] = (f16)f2.w;
      b1[4] = (f16)f3.x; b1[5] = (f16)f3.y; b1[6] = (f16)f3.z; b1[7] = (f16)f3.w;
      *(fh8*)&Bsh[r * GSTR + sc]     = b0;
      *(fh8*)&Bsh[r * GSTR + sc + 8] = b1;
    }
    __syncthreads();

#pragma unroll
    for (int ks = 0; ks < 2; ++ks) {
      fh8 af[4], bfr[4];
#pragma unroll
      for (int mt = 0; mt < 4; ++mt)
        af[mt] = *(const fh8*)&Ash[(wm * 64 + mt * 16 + q16) * GSTR + ks * 32 + quad * 8];
#pragma unroll
      for (int nt = 0; nt < 4; ++nt)
        bfr[nt] = *(const fh8*)&Bsh[(wn * 64 + nt * 16 + q16) * GSTR + ks * 32 + quad * 8];
#pragma unroll
      for (int nt = 0; nt < 4; ++nt)
#pragma unroll
        for (int mt = 0; mt < 4; ++mt)
          acc[mt][nt] = __builtin_amdgcn_mfma_f32_16x16x32_f16(af[mt], bfr[nt], acc[mt][nt], 0, 0, 0);
    }
  }

  float bsv[4];
#pragma unroll
  for (int nt = 0; nt < 4; ++nt) bsv[nt] = bias[n_blk + wn * 64 + nt * 16 + q16];

  if (MODE == 0) {
#pragma unroll
    for (int mt = 0; mt < 4; ++mt)
#pragma unroll
      for (int r = 0; r < 4; ++r) {
        int row = m_blk + wm * 64 + mt * 16 + quad * 4 + r;
#pragma unroll
        for (int nt = 0; nt < 4; ++nt) {
          int col = n_blk + wn * 64 + nt * 16 + q16;
          Cp[(size_t)row * N + col] = acc[mt][nt][r] + bsv[nt];
        }
      }
  } else {
    const int n0 = n_blk + wn * 64;
    const int which = n0 >> 10;
    const int hd = (n0 & 1023) >> 6;
    const float scale = (which == 0) ? 0.125f * LOG2E : 1.0f;
#pragma unroll
    for (int mt = 0; mt < 4; ++mt)
#pragma unroll
      for (int r = 0; r < 4; ++r) {
        int m = m_blk + wm * 64 + mt * 16 + quad * 4 + r;
        int b = m >> 11, s = m & (Sq - 1);
#pragma unroll
        for (int nt = 0; nt < 4; ++nt) {
          int d = nt * 16 + q16;
          float x = (acc[mt][nt][r] + bsv[nt]) * scale;
          if (which == 2) {  // V transposed: (B,H,DH,S)
            vto[(((size_t)(b * Hh + hd)) * DHd + d) * Sq + s] = (f16)x;
          } else {
            f16* dst = (which == 0) ? qo : ko;
            dst[(((size_t)(b * Hh + hd)) * Sq + s) * DHd + d] = (f16)x;
          }
        }
      }
  }
}

// ---------------------------------------------------------------------------
// Flash attention v3: swapped-QK 32x32 MFMA, register-resident P softmax,
// + coalesced LDS staging of K / V^T tiles (XOR-swizzled, conflict-free),
// + async stage split (next-tile global loads in flight during compute).
//   - S^T = mfma(K_frag, Q_frag): lane owns q-row = lane&31; key = C-row.
//   - p = exp2(s' + lf), lf from packed per-column attr (pid in mantissa LSBs).
//   - P -> PV B-frag via pack f16 pairs + permlane32_swap (no LDS for P).
//   - Row sum: per-lane f32 sum of the f16-quantized P (exact numerator
//     consistency), single shfl_xor(32) at the end.
// ---------------------------------------------------------------------------
__global__ __launch_bounds__(256, 2) void attn_v3(
    const f16* __restrict__ Qf, const f16* __restrict__ Kf,
    const f16* __restrict__ Vt, const int* __restrict__ pidr,
    const float* __restrict__ cattr, f16* __restrict__ attf) {
  const int qb = blockIdx.x, hd = blockIdx.y, b = blockIdx.z;
  const int bh = b * Hh + hd;
  const int tid = threadIdx.x;
  const int lane = tid & 63, w = tid >> 6;
  const int l31 = lane & 31, hi = lane >> 5;

  __shared__ __align__(16) f16 Ks[64 * 64];  // keys x d, swizzled
  __shared__ __align__(16) f16 Vs[64 * 64];  // d x keys, swizzled

  const size_t qkbase = (size_t)bh * Sq * DHd;   // (b,h,s,d)
  const size_t vtbase = (size_t)bh * DHd * Sq;   // (b,h,d,s)
  const int qrow = qb * 128 + w * 32 + l31;

  // Q B-frags for whole sweep: B[col=q=l31][k = ds*16 + hi*8 + j]
  fh8 qf[4];
  {
    const f16* qp = &Qf[qkbase + (size_t)qrow * DHd + hi * 8];
#pragma unroll
    for (int ds = 0; ds < 4; ++ds) qf[ds] = *(const fh8*)&qp[ds * 16];
  }

  const int rq = pidr[b * Sq + qrow];
  const bool isq = (rq < 0);
  const int rqp = rq + 2;  // matches packed pid+2; rq=8 -> 10 never matches

  fx16 o_acc[2];
#pragma unroll
  for (int r = 0; r < 16; ++r) { o_acc[0][r] = 0.f; o_acc[1][r] = 0.f; }
  float lsum = 0.f;

  // staging assignment: thread covers row sr, 32B at col sc (2x fh8)
  const int sr = tid >> 2, sc = (tid & 3) * 16;

  // prologue: issue tile-0 global loads
  fh8 kc0, kc1, vc0, vc1, kn0, kn1, vn0, vn1;
  {
    const f16* gk = &Kf[qkbase + (size_t)sr * DHd + sc];
    kc0 = *(const fh8*)&gk[0]; kc1 = *(const fh8*)&gk[8];
    const f16* gv = &Vt[vtbase + (size_t)sr * Sq + sc];
    vc0 = *(const fh8*)&gv[0]; vc1 = *(const fh8*)&gv[8];
  }

  const int NT = Sq / 64;
  for (int kt = 0; kt < NT; ++kt) {
    __syncthreads();  // prior iter's LDS reads done before restage
    *(fh8*)&Ks[SWZ(sr, sc)]     = kc0;
    *(fh8*)&Ks[SWZ(sr, sc + 8)] = kc1;
    *(fh8*)&Vs[SWZ(sr, sc)]     = vc0;
    *(fh8*)&Vs[SWZ(sr, sc + 8)] = vc1;
    if (kt + 1 < NT) {  // next-tile loads in flight during compute (T14)
      const f16* gk = &Kf[qkbase + (size_t)((kt + 1) * 64 + sr) * DHd + sc];
      kn0 = *(const fh8*)&gk[0]; kn1 = *(const fh8*)&gk[8];
      const f16* gv = &Vt[vtbase + (size_t)sr * Sq + (kt + 1) * 64 + sc];
      vn0 = *(const fh8*)&gv[0]; vn1 = *(const fh8*)&gv[8];
    }
    __syncthreads();

#pragma unroll
    for (int s = 0; s < 2; ++s) {
      // column attrs for this lane's 16 keys: key = s*32 + 4*hi + 8g + j
      float at[16];
      {
        const float* cp = &cattr[b * Sq + kt * 64 + s * 32 + 4 * hi];
#pragma unroll
        for (int g = 0; g < 4; ++g) {
          float4 a4 = *(const float4*)&cp[8 * g];
          at[4 * g + 0] = a4.x; at[4 * g + 1] = a4.y;
          at[4 * g + 2] = a4.z; at[4 * g + 3] = a4.w;
        }
      }

      // ---- QK (swapped): sacc[r] = S^T[key][q] ----
      fh8 kfr[4];
#pragma unroll
      for (int ds = 0; ds < 4; ++ds)
        kfr[ds] = *(const fh8*)&Ks[SWZ(s * 32 + l31, ds * 16 + hi * 8)];
      fx16 sacc;
#pragma unroll
      for (int r = 0; r < 16; ++r) sacc[r] = 0.f;
#pragma unroll
      for (int ds = 0; ds < 4; ++ds)
        sacc = __builtin_amdgcn_mfma_f32_32x32x16_f16(kfr[ds], qf[ds], sacc, 0, 0, 0);

      // ---- mask + exp (log-domain), pack f16 pairs ----
      int pk[8];
#pragma unroll
      for (int i = 0; i < 8; ++i) {
        fh2 h;
#pragma unroll
        for (int u = 0; u < 2; ++u) {
          int r = 2 * i + u;
          int bits = __float_as_int(at[r]);
          float lfq = __int_as_float(bits & ~15);
          float lfn = ((bits & 15) == rqp) ? LOG2E : 0.0f;
          float lf = isq ? lfq : lfn;
          h[u] = (f16)exp2f(sacc[r] + lf);
        }
        pk[i] = __builtin_bit_cast(int, h);
        fh2 hb = __builtin_bit_cast(fh2, pk[i]);
        lsum += (float)hb[0] + (float)hb[1];  // f16-consistent row-sum
      }

      // ---- V^T A-frags from LDS ----
      fh8 vfr[2][2];
#pragma unroll
      for (int dt = 0; dt < 2; ++dt)
#pragma unroll
        for (int kb = 0; kb < 2; ++kb)
          vfr[dt][kb] = *(const fh8*)&Vs[SWZ(dt * 32 + l31, s * 32 + kb * 16 + hi * 8)];

      // ---- assemble P B-frags + PV MFMAs ----
#pragma unroll
      for (int kb = 0; kb < 2; ++kb) {
        int a01 = pk[4 * kb + 0], a23 = pk[4 * kb + 1];
        int a45 = pk[4 * kb + 2], a67 = pk[4 * kb + 3];
        i4 t;
#if __has_builtin(__builtin_amdgcn_permlane32_swap)
        auto s0 = __builtin_amdgcn_permlane32_swap(a01, a45, false, false);
        auto s1 = __builtin_amdgcn_permlane32_swap(a23, a67, false, false);
        t[0] = s0[0]; t[1] = s1[0]; t[2] = s0[1]; t[3] = s1[1];
#else
        int x01 = __shfl_xor(a01, 32), x23 = __shfl_xor(a23, 32);
        int x45 = __shfl_xor(a45, 32), x67 = __shfl_xor(a67, 32);
        t[0] = hi ? x45 : a01; t[1] = hi ? x67 : a23;
        t[2] = hi ? a45 : x01; t[3] = hi ? a67 : x23;
#endif
        fh8 pf = __builtin_bit_cast(fh8, t);
        o_acc[0] = __builtin_amdgcn_mfma_f32_32x32x16_f16(vfr[0][kb], pf, o_acc[0], 0, 0, 0);
        o_acc[1] = __builtin_amdgcn_mfma_f32_32x32x16_f16(vfr[1][kb], pf, o_acc[1], 0, 0, 0);
      }
    }

    kc0 = kn0; kc1 = kn1; vc0 = vn0; vc1 = vn1;
  }

  // epilogue: complete row sum across the two half-wave key partitions
  float l = lsum + __shfl_xor(lsum, 32);
  float inv = 1.0f / l;
  size_t obase = ((size_t)(b * Sq + qrow)) * Eq + hd * 64 + 4 * hi;
#pragma unroll
  for (int dt = 0; dt < 2; ++dt)
#pragma unroll
    for (int g = 0; g < 4; ++g) {
      fh4 o4;
#pragma unroll
      for (int j = 0; j < 4; ++j) o4[j] = (f16)(o_acc[dt][4 * g + j] * inv);
      *(fh4*)&attf[obase + dt * 32 + 8 * g] = o4;
    }
}

// ---------------------------------------------------------------------------
extern "C" void kernel_launch(void* const* d_in, const int* in_sizes, int n_in,
                              void* d_out, int out_size, void* d_ws, size_t ws_size,
                              hipStream_t stream) {
  const float* hs = (const float*)d_in[0];
  const float* rel = (const float*)d_in[1];
  const int* bnd = (const int*)d_in[2];
  const float* wi = (const float*)d_in[3];
  const float* bi = (const float*)d_in[4];
  const float* wo = (const float*)d_in[5];
  const float* bo = (const float*)d_in[6];
  float* out = (float*)d_out;

  const size_t NQ = (size_t)Bsz * Hh * Sq * DHd;  // 8,388,608 (== B*S*E)
  char* p = (char*)d_ws;
  f16* qf = (f16*)p;   p += NQ * 2;
  f16* kf = (f16*)p;   p += NQ * 2;
  f16* vt = (f16*)p;   p += NQ * 2;
  f16* hsf = (f16*)p;  p += NQ * 2;
  f16* attf = (f16*)p; p += NQ * 2;
  int* pidr = (int*)p; p += Bsz * Sq * 4;
  float* cattr = (float*)p;

  hipLaunchKernelGGL(pid_kernel, dim3((Bsz * Sq + 255) / 256), dim3(256), 0, stream,
                     bnd, rel, pidr, cattr);
  hipLaunchKernelGGL(cvt_hs, dim3((int)(NQ / 8 / 256)), dim3(256), 0, stream,
                     hs, hsf);
  hipLaunchKernelGGL((gemm_f16<1>), dim3(24, 64), dim3(256), 0, stream,
                     hsf, wi, bi, (float*)nullptr, Bsz * Sq, 3 * Eq, Eq,
                     qf, kf, vt);
  hipLaunchKernelGGL(attn_v3, dim3(16, 16, 4), dim3(256), 0, stream,
                     qf, kf, vt, pidr, cattr, attf);
  hipLaunchKernelGGL((gemm_f16<0>), dim3(8, 64), dim3(256), 0, stream,
                     attf, wo, bo, out, Bsz * Sq, Eq, Eq,
                     nullptr, nullptr, nullptr);
}

// Round 3
// 333.326 us; speedup vs baseline: 1.6715x; 1.1885x over previous
//
#include <hip/hip_runtime.h>
#include <math.h>

#define Bsz 4
#define Sq  2048
#define Eq  1024
#define Hh  16
#define DHd 64
#define Kb  9
#define GSTR 72  // gemm LDS row stride (halves)
#define LOG2E 1.44269504088896340736f
#define NCLS 10  // row classes: query(-1) + pids 0..8

typedef _Float16 f16;
typedef __attribute__((ext_vector_type(8))) _Float16 fh8;   // MFMA A/B frag (4 VGPRs)
typedef __attribute__((ext_vector_type(4))) _Float16 fh4;
typedef __attribute__((ext_vector_type(2))) _Float16 fh2;
typedef __attribute__((ext_vector_type(4))) float fx4;      // 16x16 C/D frag
typedef __attribute__((ext_vector_type(16))) float fx16;    // 32x32 C/D frag
typedef __attribute__((ext_vector_type(4))) int i4;

// LDS swizzle: 64-half rows (128 B) -> XOR row into 16B-chunk index.
#define SWZ(r, c) ((r) * 64 + ((c) ^ (((r) & 7) << 3)))

static __device__ __forceinline__ float fexp2(float x) {
#if __has_builtin(__builtin_amdgcn_exp2f)
  return __builtin_amdgcn_exp2f(x);   // raw v_exp_f32
#else
  return __expf(x * 0.6931471805599453f);
#endif
}

// ---------------------------------------------------------------------------
// passage id per row + additive log2-mask table lfTab[b][cls][col]:
//   cls 0   : query rows  -> colval(col) * log2e
//   cls 1+j : rows in passage j -> log2e if col in passage j else 0
//   (cls 9, rq=8: all zeros, falls out of the same formula)
// ---------------------------------------------------------------------------
__global__ void pid_kernel(const int* __restrict__ bnd, const float* __restrict__ rel,
                           int* __restrict__ pidr, float* __restrict__ lfTab) {
  int idx = blockIdx.x * blockDim.x + threadIdx.x;
  if (idx >= Bsz * Sq) return;
  int b = idx >> 11;
  int s = idx & (Sq - 1);
  int j = -1;
#pragma unroll
  for (int t = 0; t < Kb; ++t) {
    if (bnd[b * Kb + t] <= s) j = t;
  }
  pidr[idx] = j;
  bool inp = (j >= 0 && j < Kb - 1);
  float cv = inp ? rel[b * (Kb - 1) + j] : 1.0f;
  float* base = &lfTab[(size_t)b * NCLS * Sq + s];
  base[0] = cv * LOG2E;  // query-row class
#pragma unroll
  for (int c = 1; c < NCLS; ++c)
    base[c * Sq] = (inp && j == c - 1) ? LOG2E : 0.0f;
}

// ---------------------------------------------------------------------------
// fp32 -> fp16 cast, 8 elems/thread
// ---------------------------------------------------------------------------
__global__ __launch_bounds__(256) void cvt_hs(const float* __restrict__ x,
                                              f16* __restrict__ xo) {
  int i = (blockIdx.x * blockDim.x + threadIdx.x) * 8;
  float4 a = *(const float4*)&x[i];
  float4 b = *(const float4*)&x[i + 4];
  fh8 o;
  o[0] = (f16)a.x; o[1] = (f16)a.y; o[2] = (f16)a.z; o[3] = (f16)a.w;
  o[4] = (f16)b.x; o[5] = (f16)b.y; o[6] = (f16)b.z; o[7] = (f16)b.w;
  *(fh8*)&xo[i] = o;
}

// ---------------------------------------------------------------------------
// fp16 MFMA GEMM: C = A * B^T + bias  (structure unchanged)
// MODE 1: q additionally scaled by 0.125*log2(e) so attn can use exp2.
// ---------------------------------------------------------------------------
template <int MODE>
__global__ __launch_bounds__(256) void gemm_f16(
    const f16* __restrict__ A, const float* __restrict__ Bf,
    const float* __restrict__ bias, float* __restrict__ Cp,
    int M, int N, int Kd,
    f16* __restrict__ qo, f16* __restrict__ ko, f16* __restrict__ vto) {
  __shared__ __align__(16) f16 Ash[128 * GSTR];
  __shared__ __align__(16) f16 Bsh[128 * GSTR];

  const int tid = threadIdx.x;
  const int lane = tid & 63, w = tid >> 6;
  const int wm = w >> 1, wn = w & 1;
  const int q16 = lane & 15, quad = lane >> 4;
  const int m_blk = blockIdx.y * 128, n_blk = blockIdx.x * 128;

  fx4 acc[4][4];
#pragma unroll
  for (int mt = 0; mt < 4; ++mt)
#pragma unroll
    for (int nt = 0; nt < 4; ++nt)
#pragma unroll
      for (int r = 0; r < 4; ++r) acc[mt][nt][r] = 0.f;

  const int sr = tid >> 2, sc = (tid & 3) * 16;

  for (int k0 = 0; k0 < Kd; k0 += 64) {
    __syncthreads();
#pragma unroll
    for (int h = 0; h < 2; ++h) {
      const int r = sr + h * 64;
      const f16* ga = &A[(size_t)(m_blk + r) * Kd + k0 + sc];
      *(fh8*)&Ash[r * GSTR + sc]     = *(const fh8*)&ga[0];
      *(fh8*)&Ash[r * GSTR + sc + 8] = *(const fh8*)&ga[8];
      const float* gb = &Bf[(size_t)(n_blk + r) * Kd + k0 + sc];
      float4 f0 = *(const float4*)&gb[0];
      float4 f1 = *(const float4*)&gb[4];
      float4 f2 = *(const float4*)&gb[8];
      float4 f3 = *(const float4*)&gb[12];
      fh8 b0, b1;
      b0[0] = (f16)f0.x; b0[1] = (f16)f0.y; b0[2] = (f16)f0.z; b0[3] = (f16)f0.w;
      b0[4] = (f16)f1.x; b0[5] = (f16)f1.y; b0[6] = (f16)f1.z; b0[7] = (f16)f1.w;
      b1[0] = (f16)f2.x; b1[1] = (f16)f2.y; b1[2] = (f16)f2.z; b1[3] = (f16)f2.w;
      b1[4] = (f16)f3.x; b1[5] = (f16)f3.y; b1[6] = (f16)f3.z; b1[7] = (f16)f3.w;
      *(fh8*)&Bsh[r * GSTR + sc]     = b0;
      *(fh8*)&Bsh[r * GSTR + sc + 8] = b1;
    }
    __syncthreads();

#pragma unroll
    for (int ks = 0; ks < 2; ++ks) {
      fh8 af[4], bfr[4];
#pragma unroll
      for (int mt = 0; mt < 4; ++mt)
        af[mt] = *(const fh8*)&Ash[(wm * 64 + mt * 16 + q16) * GSTR + ks * 32 + quad * 8];
#pragma unroll
      for (int nt = 0; nt < 4; ++nt)
        bfr[nt] = *(const fh8*)&Bsh[(wn * 64 + nt * 16 + q16) * GSTR + ks * 32 + quad * 8];
#pragma unroll
      for (int nt = 0; nt < 4; ++nt)
#pragma unroll
        for (int mt = 0; mt < 4; ++mt)
          acc[mt][nt] = __builtin_amdgcn_mfma_f32_16x16x32_f16(af[mt], bfr[nt], acc[mt][nt], 0, 0, 0);
    }
  }

  float bsv[4];
#pragma unroll
  for (int nt = 0; nt < 4; ++nt) bsv[nt] = bias[n_blk + wn * 64 + nt * 16 + q16];

  if (MODE == 0) {
#pragma unroll
    for (int mt = 0; mt < 4; ++mt)
#pragma unroll
      for (int r = 0; r < 4; ++r) {
        int row = m_blk + wm * 64 + mt * 16 + quad * 4 + r;
#pragma unroll
        for (int nt = 0; nt < 4; ++nt) {
          int col = n_blk + wn * 64 + nt * 16 + q16;
          Cp[(size_t)row * N + col] = acc[mt][nt][r] + bsv[nt];
        }
      }
  } else {
    const int n0 = n_blk + wn * 64;
    const int which = n0 >> 10;
    const int hd = (n0 & 1023) >> 6;
    const float scale = (which == 0) ? 0.125f * LOG2E : 1.0f;
#pragma unroll
    for (int mt = 0; mt < 4; ++mt)
#pragma unroll
      for (int r = 0; r < 4; ++r) {
        int m = m_blk + wm * 64 + mt * 16 + quad * 4 + r;
        int b = m >> 11, s = m & (Sq - 1);
#pragma unroll
        for (int nt = 0; nt < 4; ++nt) {
          int d = nt * 16 + q16;
          float x = (acc[mt][nt][r] + bsv[nt]) * scale;
          if (which == 2) {  // V transposed: (B,H,DH,S)
            vto[(((size_t)(b * Hh + hd)) * DHd + d) * Sq + s] = (f16)x;
          } else {
            f16* dst = (which == 0) ? qo : ko;
            dst[(((size_t)(b * Hh + hd)) * Sq + s) * DHd + d] = (f16)x;
          }
        }
      }
  }
}

// ---------------------------------------------------------------------------
// Flash attention v4: swapped-QK 32x32 MFMA, register-resident P.
//   vs v3: raw v_exp_f32; mask preloaded as MFMA C-init from lfTab;
//   row-sum via ones-row MFMA (MFMA pipe, not VALU); double-buffered LDS
//   with ONE barrier per 64-key tile.
// ---------------------------------------------------------------------------
__global__ __launch_bounds__(256, 2) void attn_v4(
    const f16* __restrict__ Qf, const f16* __restrict__ Kf,
    const f16* __restrict__ Vt, const int* __restrict__ pidr,
    const float* __restrict__ lfTab, f16* __restrict__ attf) {
  const int qb = blockIdx.x, hd = blockIdx.y, b = blockIdx.z;
  const int bh = b * Hh + hd;
  const int tid = threadIdx.x;
  const int lane = tid & 63, w = tid >> 6;
  const int l31 = lane & 31, hi = lane >> 5;

  __shared__ __align__(16) f16 Ks[2][64 * 64];
  __shared__ __align__(16) f16 Vs[2][64 * 64];

  const size_t qkbase = (size_t)bh * Sq * DHd;   // (b,h,s,d)
  const size_t vtbase = (size_t)bh * DHd * Sq;   // (b,h,d,s)
  const int qrow = qb * 128 + w * 32 + l31;

  // Q B-frags for whole sweep: B[col=q=l31][k = ds*16 + hi*8 + j]
  fh8 qf[4];
  {
    const f16* qp = &Qf[qkbase + (size_t)qrow * DHd + hi * 8];
#pragma unroll
    for (int ds = 0; ds < 4; ++ds) qf[ds] = *(const fh8*)&qp[ds * 16];
  }

  // per-lane additive-log mask row (class = rq+1), pre-offset by 4*hi
  const int rq = pidr[b * Sq + qrow];
  const float* lfrow = &lfTab[((size_t)(b * NCLS + (rq + 1))) * Sq + 4 * hi];

  // ones A-frag: row 0 only -> C row0 = per-q P row-sums
  fh8 onesf;
#pragma unroll
  for (int j = 0; j < 8; ++j) onesf[j] = (l31 == 0) ? (f16)1.0f : (f16)0.0f;

  fx16 o_acc[2], lacc;
#pragma unroll
  for (int r = 0; r < 16; ++r) { o_acc[0][r] = 0.f; o_acc[1][r] = 0.f; lacc[r] = 0.f; }

  // staging: thread covers row sr, 32B at col sc (2x fh8)
  const int sr = tid >> 2, sc = (tid & 3) * 16;
  const int NT = Sq / 64;

  // prologue: tile0 -> buf0; tile1 loads in flight
  fh8 kc0, kc1, vc0, vc1;
  {
    const f16* gk = &Kf[qkbase + (size_t)sr * DHd + sc];
    kc0 = *(const fh8*)&gk[0]; kc1 = *(const fh8*)&gk[8];
    const f16* gv = &Vt[vtbase + (size_t)sr * Sq + sc];
    vc0 = *(const fh8*)&gv[0]; vc1 = *(const fh8*)&gv[8];
  }
  *(fh8*)&Ks[0][SWZ(sr, sc)]     = kc0;
  *(fh8*)&Ks[0][SWZ(sr, sc + 8)] = kc1;
  *(fh8*)&Vs[0][SWZ(sr, sc)]     = vc0;
  *(fh8*)&Vs[0][SWZ(sr, sc + 8)] = vc1;
  {
    const f16* gk = &Kf[qkbase + (size_t)(64 + sr) * DHd + sc];
    kc0 = *(const fh8*)&gk[0]; kc1 = *(const fh8*)&gk[8];
    const f16* gv = &Vt[vtbase + (size_t)sr * Sq + 64 + sc];
    vc0 = *(const fh8*)&gv[0]; vc1 = *(const fh8*)&gv[8];
  }
  __syncthreads();

  fx16 sacc0, sacc1;

  for (int kt = 0; kt < NT; ++kt) {
    const int c = kt & 1;

    // issue s=0 mask loads early (C-init of QK MFMA)
    {
      const float* lp = &lfrow[kt * 64];
#pragma unroll
      for (int g = 0; g < 4; ++g) {
        float4 a = *(const float4*)&lp[8 * g];
        sacc0[4 * g + 0] = a.x; sacc0[4 * g + 1] = a.y;
        sacc0[4 * g + 2] = a.z; sacc0[4 * g + 3] = a.w;
      }
    }

    // stage tile kt+1 into the other buffer; issue loads for tile kt+2
    if (kt + 1 < NT) {
      *(fh8*)&Ks[c ^ 1][SWZ(sr, sc)]     = kc0;
      *(fh8*)&Ks[c ^ 1][SWZ(sr, sc + 8)] = kc1;
      *(fh8*)&Vs[c ^ 1][SWZ(sr, sc)]     = vc0;
      *(fh8*)&Vs[c ^ 1][SWZ(sr, sc + 8)] = vc1;
      if (kt + 2 < NT) {
        const f16* gk = &Kf[qkbase + (size_t)((kt + 2) * 64 + sr) * DHd + sc];
        kc0 = *(const fh8*)&gk[0]; kc1 = *(const fh8*)&gk[8];
        const f16* gv = &Vt[vtbase + (size_t)sr * Sq + (kt + 2) * 64 + sc];
        vc0 = *(const fh8*)&gv[0]; vc1 = *(const fh8*)&gv[8];
      }
    }

    auto half = [&](fx16& sacc, int s, bool preload_next) {
      // ---- QK (swapped): sacc starts as additive log-mask ----
      fh8 kfr[4];
#pragma unroll
      for (int ds = 0; ds < 4; ++ds)
        kfr[ds] = *(const fh8*)&Ks[c][SWZ(s * 32 + l31, ds * 16 + hi * 8)];
#pragma unroll
      for (int ds = 0; ds < 4; ++ds)
        sacc = __builtin_amdgcn_mfma_f32_32x32x16_f16(kfr[ds], qf[ds], sacc, 0, 0, 0);

      if (preload_next) {  // s=1 mask loads hide under s=0 exp/PV
        const float* lp = &lfrow[kt * 64 + 32];
#pragma unroll
        for (int g = 0; g < 4; ++g) {
          float4 a = *(const float4*)&lp[8 * g];
          sacc1[4 * g + 0] = a.x; sacc1[4 * g + 1] = a.y;
          sacc1[4 * g + 2] = a.z; sacc1[4 * g + 3] = a.w;
        }
      }

      // ---- exp (raw v_exp_f32) + pack f16 pairs ----
      int pk[8];
#pragma unroll
      for (int i = 0; i < 8; ++i) {
        fh2 h;
        h[0] = (f16)fexp2(sacc[2 * i]);
        h[1] = (f16)fexp2(sacc[2 * i + 1]);
        pk[i] = __builtin_bit_cast(int, h);
      }

      // ---- V^T A-frags from LDS ----
      fh8 vfr[2][2];
#pragma unroll
      for (int dt = 0; dt < 2; ++dt)
#pragma unroll
        for (int kb = 0; kb < 2; ++kb)
          vfr[dt][kb] = *(const fh8*)&Vs[c][SWZ(dt * 32 + l31, s * 32 + kb * 16 + hi * 8)];

      // ---- P B-frags via permlane; row-sum + PV on MFMA pipe ----
#pragma unroll
      for (int kb = 0; kb < 2; ++kb) {
        int a01 = pk[4 * kb + 0], a23 = pk[4 * kb + 1];
        int a45 = pk[4 * kb + 2], a67 = pk[4 * kb + 3];
        i4 t;
#if __has_builtin(__builtin_amdgcn_permlane32_swap)
        auto s0 = __builtin_amdgcn_permlane32_swap(a01, a45, false, false);
        auto s1 = __builtin_amdgcn_permlane32_swap(a23, a67, false, false);
        t[0] = s0[0]; t[1] = s1[0]; t[2] = s0[1]; t[3] = s1[1];
#else
        int x01 = __shfl_xor(a01, 32), x23 = __shfl_xor(a23, 32);
        int x45 = __shfl_xor(a45, 32), x67 = __shfl_xor(a67, 32);
        t[0] = hi ? x45 : a01; t[1] = hi ? x67 : a23;
        t[2] = hi ? a45 : x01; t[3] = hi ? a67 : x23;
#endif
        fh8 pf = __builtin_bit_cast(fh8, t);
        lacc = __builtin_amdgcn_mfma_f32_32x32x16_f16(onesf, pf, lacc, 0, 0, 0);
        o_acc[0] = __builtin_amdgcn_mfma_f32_32x32x16_f16(vfr[0][kb], pf, o_acc[0], 0, 0, 0);
        o_acc[1] = __builtin_amdgcn_mfma_f32_32x32x16_f16(vfr[1][kb], pf, o_acc[1], 0, 0, 0);
      }
    };

    half(sacc0, 0, true);
    half(sacc1, 1, false);

    if (kt + 1 < NT) __syncthreads();
  }

  // epilogue: row sum in C row0 (reg0 of hi=0 lanes); broadcast by q
  float l = __shfl(lacc[0], l31);
  float inv = 1.0f / l;
  size_t obase = ((size_t)(b * Sq + qrow)) * Eq + hd * 64 + 4 * hi;
#pragma unroll
  for (int dt = 0; dt < 2; ++dt)
#pragma unroll
    for (int g = 0; g < 4; ++g) {
      fh4 o4;
#pragma unroll
      for (int j = 0; j < 4; ++j) o4[j] = (f16)(o_acc[dt][4 * g + j] * inv);
      *(fh4*)&attf[obase + dt * 32 + 8 * g] = o4;
    }
}

// ---------------------------------------------------------------------------
extern "C" void kernel_launch(void* const* d_in, const int* in_sizes, int n_in,
                              void* d_out, int out_size, void* d_ws, size_t ws_size,
                              hipStream_t stream) {
  const float* hs = (const float*)d_in[0];
  const float* rel = (const float*)d_in[1];
  const int* bnd = (const int*)d_in[2];
  const float* wi = (const float*)d_in[3];
  const float* bi = (const float*)d_in[4];
  const float* wo = (const float*)d_in[5];
  const float* bo = (const float*)d_in[6];
  float* out = (float*)d_out;

  const size_t NQ = (size_t)Bsz * Hh * Sq * DHd;  // 8,388,608 (== B*S*E)
  char* p = (char*)d_ws;
  f16* qf = (f16*)p;   p += NQ * 2;
  f16* kf = (f16*)p;   p += NQ * 2;
  f16* vt = (f16*)p;   p += NQ * 2;
  f16* hsf = (f16*)p;  p += NQ * 2;
  f16* attf = (f16*)p; p += NQ * 2;
  int* pidr = (int*)p; p += Bsz * Sq * 4;
  float* lfTab = (float*)p;  // Bsz*NCLS*Sq*4 = 327KB

  hipLaunchKernelGGL(pid_kernel, dim3((Bsz * Sq + 255) / 256), dim3(256), 0, stream,
                     bnd, rel, pidr, lfTab);
  hipLaunchKernelGGL(cvt_hs, dim3((int)(NQ / 8 / 256)), dim3(256), 0, stream,
                     hs, hsf);
  hipLaunchKernelGGL((gemm_f16<1>), dim3(24, 64), dim3(256), 0, stream,
                     hsf, wi, bi, (float*)nullptr, Bsz * Sq, 3 * Eq, Eq,
                     qf, kf, vt);
  hipLaunchKernelGGL(attn_v4, dim3(16, 16, 4), dim3(256), 0, stream,
                     qf, kf, vt, pidr, lfTab, attf);
  hipLaunchKernelGGL((gemm_f16<0>), dim3(8, 64), dim3(256), 0, stream,
                     attf, wo, bo, out, Bsz * Sq, Eq, Eq,
                     nullptr, nullptr, nullptr);
}

// Round 4
// 312.125 us; speedup vs baseline: 1.7851x; 1.0679x over previous
//
#include <hip/hip_runtime.h>
#include <math.h>

#define Bsz 4
#define Sq  2048
#define Eq  1024
#define Hh  16
#define DHd 64
#define Kb  9
#define LOG2E 1.44269504088896340736f
#define NCLS 10  // row classes: query(-1) + pids 0..8

typedef _Float16 f16;
typedef __attribute__((ext_vector_type(8))) _Float16 fh8;   // MFMA A/B frag (4 VGPRs)
typedef __attribute__((ext_vector_type(4))) _Float16 fh4;
typedef __attribute__((ext_vector_type(2))) _Float16 fh2;
typedef __attribute__((ext_vector_type(4))) float fx4;      // 16x16 C/D frag
typedef __attribute__((ext_vector_type(16))) float fx16;    // 32x32 C/D frag
typedef __attribute__((ext_vector_type(4))) int i4;

// LDS swizzle: 64-half rows (128 B) -> XOR row into 16B-chunk index.
// Reads of consecutive rows at fixed col land in distinct chunks (<=2-way).
#define SWZ(r, c) ((r) * 64 + ((c) ^ (((r) & 7) << 3)))

static __device__ __forceinline__ float fexp2(float x) {
#if __has_builtin(__builtin_amdgcn_exp2f)
  return __builtin_amdgcn_exp2f(x);   // raw v_exp_f32
#else
  return __expf(x * 0.6931471805599453f);
#endif
}

// ---------------------------------------------------------------------------
// passage id per row + additive log2-mask table lfTab[b][cls][col]:
//   cls 0   : query rows  -> colval(col) * log2e
//   cls 1+j : rows in passage j -> log2e if col in passage j else 0
// ---------------------------------------------------------------------------
__global__ void pid_kernel(const int* __restrict__ bnd, const float* __restrict__ rel,
                           int* __restrict__ pidr, float* __restrict__ lfTab) {
  int idx = blockIdx.x * blockDim.x + threadIdx.x;
  if (idx >= Bsz * Sq) return;
  int b = idx >> 11;
  int s = idx & (Sq - 1);
  int j = -1;
#pragma unroll
  for (int t = 0; t < Kb; ++t) {
    if (bnd[b * Kb + t] <= s) j = t;
  }
  pidr[idx] = j;
  bool inp = (j >= 0 && j < Kb - 1);
  float cv = inp ? rel[b * (Kb - 1) + j] : 1.0f;
  float* base = &lfTab[(size_t)b * NCLS * Sq + s];
  base[0] = cv * LOG2E;  // query-row class
#pragma unroll
  for (int c = 1; c < NCLS; ++c)
    base[c * Sq] = (inp && j == c - 1) ? LOG2E : 0.0f;
}

// ---------------------------------------------------------------------------
// fp32 -> fp16 cast, 8 elems/thread (used for hs, wi, wo)
// ---------------------------------------------------------------------------
__global__ __launch_bounds__(256) void cvt_hs(const float* __restrict__ x,
                                              f16* __restrict__ xo) {
  int i = (blockIdx.x * blockDim.x + threadIdx.x) * 8;
  float4 a = *(const float4*)&x[i];
  float4 b = *(const float4*)&x[i + 4];
  fh8 o;
  o[0] = (f16)a.x; o[1] = (f16)a.y; o[2] = (f16)a.z; o[3] = (f16)a.w;
  o[4] = (f16)b.x; o[5] = (f16)b.y; o[6] = (f16)b.z; o[7] = (f16)b.w;
  *(fh8*)&xo[i] = o;
}

// ---------------------------------------------------------------------------
// fp16 MFMA GEMM v2: C = A * B^T + bias, A and B both fp16.
//   128x128x64 tile, 4 waves 2x2, 16x16x32 MFMA.
//   Register-prefetch pipeline: K-step k+1 global loads issued right after
//   the k ds_writes -> latency hidden under MFMA phase (v3-attn pattern).
//   XOR-swizzled LDS (32 KB total, no pad).
// MODE 0: Cp[m*N+n] = acc + bias (fp32)
// MODE 1: n<1024 -> q fp16 scaled 0.125*log2e; n<2048 -> k fp16; else vt fp16^T
// ---------------------------------------------------------------------------
template <int MODE>
__global__ __launch_bounds__(256) void gemm_f16(
    const f16* __restrict__ A, const f16* __restrict__ Bh,
    const float* __restrict__ bias, float* __restrict__ Cp,
    int M, int N, int Kd,
    f16* __restrict__ qo, f16* __restrict__ ko, f16* __restrict__ vto) {
  __shared__ __align__(16) f16 Ash[128 * 64];
  __shared__ __align__(16) f16 Bsh[128 * 64];

  const int tid = threadIdx.x;
  const int lane = tid & 63, w = tid >> 6;
  const int wm = w >> 1, wn = w & 1;
  const int q16 = lane & 15, quad = lane >> 4;
  const int m_blk = blockIdx.y * 128, n_blk = blockIdx.x * 128;

  fx4 acc[4][4];
#pragma unroll
  for (int mt = 0; mt < 4; ++mt)
#pragma unroll
    for (int nt = 0; nt < 4; ++nt)
#pragma unroll
      for (int r = 0; r < 4; ++r) acc[mt][nt][r] = 0.f;

  const int sr = tid >> 2, sc = (tid & 3) * 16;

  // register-prefetch buffers: [row-half][16B chunk]
  fh8 pa[2][2], pb[2][2];
  const f16* ga0 = &A[(size_t)(m_blk + sr) * Kd + sc];
  const f16* gb0 = &Bh[(size_t)(n_blk + sr) * Kd + sc];

#pragma unroll
  for (int h = 0; h < 2; ++h) {
    const f16* ga = ga0 + (size_t)h * 64 * Kd;
    pa[h][0] = *(const fh8*)&ga[0];
    pa[h][1] = *(const fh8*)&ga[8];
    const f16* gb = gb0 + (size_t)h * 64 * Kd;
    pb[h][0] = *(const fh8*)&gb[0];
    pb[h][1] = *(const fh8*)&gb[8];
  }

  for (int k0 = 0; k0 < Kd; k0 += 64) {
    __syncthreads();  // prior iteration's LDS frag reads complete
#pragma unroll
    for (int h = 0; h < 2; ++h) {
      const int r = sr + h * 64;
      *(fh8*)&Ash[SWZ(r, sc)]     = pa[h][0];
      *(fh8*)&Ash[SWZ(r, sc + 8)] = pa[h][1];
      *(fh8*)&Bsh[SWZ(r, sc)]     = pb[h][0];
      *(fh8*)&Bsh[SWZ(r, sc + 8)] = pb[h][1];
    }
    if (k0 + 64 < Kd) {  // issue next K-step loads; in flight during MFMA
      const int kn = k0 + 64;
#pragma unroll
      for (int h = 0; h < 2; ++h) {
        const f16* ga = ga0 + (size_t)h * 64 * Kd + kn;
        pa[h][0] = *(const fh8*)&ga[0];
        pa[h][1] = *(const fh8*)&ga[8];
        const f16* gb = gb0 + (size_t)h * 64 * Kd + kn;
        pb[h][0] = *(const fh8*)&gb[0];
        pb[h][1] = *(const fh8*)&gb[8];
      }
    }
    __syncthreads();

#pragma unroll
    for (int ks = 0; ks < 2; ++ks) {
      fh8 af[4], bfr[4];
#pragma unroll
      for (int mt = 0; mt < 4; ++mt)
        af[mt] = *(const fh8*)&Ash[SWZ(wm * 64 + mt * 16 + q16, ks * 32 + quad * 8)];
#pragma unroll
      for (int nt = 0; nt < 4; ++nt)
        bfr[nt] = *(const fh8*)&Bsh[SWZ(wn * 64 + nt * 16 + q16, ks * 32 + quad * 8)];
#pragma unroll
      for (int nt = 0; nt < 4; ++nt)
#pragma unroll
        for (int mt = 0; mt < 4; ++mt)
          acc[mt][nt] = __builtin_amdgcn_mfma_f32_16x16x32_f16(af[mt], bfr[nt], acc[mt][nt], 0, 0, 0);
    }
  }

  float bsv[4];
#pragma unroll
  for (int nt = 0; nt < 4; ++nt) bsv[nt] = bias[n_blk + wn * 64 + nt * 16 + q16];

  if (MODE == 0) {
#pragma unroll
    for (int mt = 0; mt < 4; ++mt)
#pragma unroll
      for (int r = 0; r < 4; ++r) {
        int row = m_blk + wm * 64 + mt * 16 + quad * 4 + r;
#pragma unroll
        for (int nt = 0; nt < 4; ++nt) {
          int col = n_blk + wn * 64 + nt * 16 + q16;
          Cp[(size_t)row * N + col] = acc[mt][nt][r] + bsv[nt];
        }
      }
  } else {
    const int n0 = n_blk + wn * 64;  // 64-aligned -> which/hd wave-uniform
    const int which = n0 >> 10;
    const int hd = (n0 & 1023) >> 6;
    const float scale = (which == 0) ? 0.125f * LOG2E : 1.0f;
#pragma unroll
    for (int mt = 0; mt < 4; ++mt)
#pragma unroll
      for (int r = 0; r < 4; ++r) {
        int m = m_blk + wm * 64 + mt * 16 + quad * 4 + r;
        int b = m >> 11, s = m & (Sq - 1);
#pragma unroll
        for (int nt = 0; nt < 4; ++nt) {
          int d = nt * 16 + q16;
          float x = (acc[mt][nt][r] + bsv[nt]) * scale;
          if (which == 2) {  // V transposed: (B,H,DH,S)
            vto[(((size_t)(b * Hh + hd)) * DHd + d) * Sq + s] = (f16)x;
          } else {
            f16* dst = (which == 0) ? qo : ko;
            dst[(((size_t)(b * Hh + hd)) * Sq + s) * DHd + d] = (f16)x;
          }
        }
      }
  }
}

// ---------------------------------------------------------------------------
// Flash attention v4 (unchanged from round 3): swapped-QK 32x32 MFMA,
// register-resident P, raw v_exp_f32, mask as MFMA C-init, ones-row MFMA
// row-sum, double-buffered LDS with one barrier per 64-key tile.
// ---------------------------------------------------------------------------
__global__ __launch_bounds__(256, 2) void attn_v4(
    const f16* __restrict__ Qf, const f16* __restrict__ Kf,
    const f16* __restrict__ Vt, const int* __restrict__ pidr,
    const float* __restrict__ lfTab, f16* __restrict__ attf) {
  const int qb = blockIdx.x, hd = blockIdx.y, b = blockIdx.z;
  const int bh = b * Hh + hd;
  const int tid = threadIdx.x;
  const int lane = tid & 63, w = tid >> 6;
  const int l31 = lane & 31, hi = lane >> 5;

  __shared__ __align__(16) f16 Ks[2][64 * 64];
  __shared__ __align__(16) f16 Vs[2][64 * 64];

  const size_t qkbase = (size_t)bh * Sq * DHd;   // (b,h,s,d)
  const size_t vtbase = (size_t)bh * DHd * Sq;   // (b,h,d,s)
  const int qrow = qb * 128 + w * 32 + l31;

  fh8 qf[4];
  {
    const f16* qp = &Qf[qkbase + (size_t)qrow * DHd + hi * 8];
#pragma unroll
    for (int ds = 0; ds < 4; ++ds) qf[ds] = *(const fh8*)&qp[ds * 16];
  }

  const int rq = pidr[b * Sq + qrow];
  const float* lfrow = &lfTab[((size_t)(b * NCLS + (rq + 1))) * Sq + 4 * hi];

  fh8 onesf;
#pragma unroll
  for (int j = 0; j < 8; ++j) onesf[j] = (l31 == 0) ? (f16)1.0f : (f16)0.0f;

  fx16 o_acc[2], lacc;
#pragma unroll
  for (int r = 0; r < 16; ++r) { o_acc[0][r] = 0.f; o_acc[1][r] = 0.f; lacc[r] = 0.f; }

  const int sr = tid >> 2, sc = (tid & 3) * 16;
  const int NT = Sq / 64;

  fh8 kc0, kc1, vc0, vc1;
  {
    const f16* gk = &Kf[qkbase + (size_t)sr * DHd + sc];
    kc0 = *(const fh8*)&gk[0]; kc1 = *(const fh8*)&gk[8];
    const f16* gv = &Vt[vtbase + (size_t)sr * Sq + sc];
    vc0 = *(const fh8*)&gv[0]; vc1 = *(const fh8*)&gv[8];
  }
  *(fh8*)&Ks[0][SWZ(sr, sc)]     = kc0;
  *(fh8*)&Ks[0][SWZ(sr, sc + 8)] = kc1;
  *(fh8*)&Vs[0][SWZ(sr, sc)]     = vc0;
  *(fh8*)&Vs[0][SWZ(sr, sc + 8)] = vc1;
  {
    const f16* gk = &Kf[qkbase + (size_t)(64 + sr) * DHd + sc];
    kc0 = *(const fh8*)&gk[0]; kc1 = *(const fh8*)&gk[8];
    const f16* gv = &Vt[vtbase + (size_t)sr * Sq + 64 + sc];
    vc0 = *(const fh8*)&gv[0]; vc1 = *(const fh8*)&gv[8];
  }
  __syncthreads();

  fx16 sacc0, sacc1;

  for (int kt = 0; kt < NT; ++kt) {
    const int c = kt & 1;

    {
      const float* lp = &lfrow[kt * 64];
#pragma unroll
      for (int g = 0; g < 4; ++g) {
        float4 a = *(const float4*)&lp[8 * g];
        sacc0[4 * g + 0] = a.x; sacc0[4 * g + 1] = a.y;
        sacc0[4 * g + 2] = a.z; sacc0[4 * g + 3] = a.w;
      }
    }

    if (kt + 1 < NT) {
      *(fh8*)&Ks[c ^ 1][SWZ(sr, sc)]     = kc0;
      *(fh8*)&Ks[c ^ 1][SWZ(sr, sc + 8)] = kc1;
      *(fh8*)&Vs[c ^ 1][SWZ(sr, sc)]     = vc0;
      *(fh8*)&Vs[c ^ 1][SWZ(sr, sc + 8)] = vc1;
      if (kt + 2 < NT) {
        const f16* gk = &Kf[qkbase + (size_t)((kt + 2) * 64 + sr) * DHd + sc];
        kc0 = *(const fh8*)&gk[0]; kc1 = *(const fh8*)&gk[8];
        const f16* gv = &Vt[vtbase + (size_t)sr * Sq + (kt + 2) * 64 + sc];
        vc0 = *(const fh8*)&gv[0]; vc1 = *(const fh8*)&gv[8];
      }
    }

    auto half = [&](fx16& sacc, int s, bool preload_next) {
      fh8 kfr[4];
#pragma unroll
      for (int ds = 0; ds < 4; ++ds)
        kfr[ds] = *(const fh8*)&Ks[c][SWZ(s * 32 + l31, ds * 16 + hi * 8)];
#pragma unroll
      for (int ds = 0; ds < 4; ++ds)
        sacc = __builtin_amdgcn_mfma_f32_32x32x16_f16(kfr[ds], qf[ds], sacc, 0, 0, 0);

      if (preload_next) {
        const float* lp = &lfrow[kt * 64 + 32];
#pragma unroll
        for (int g = 0; g < 4; ++g) {
          float4 a = *(const float4*)&lp[8 * g];
          sacc1[4 * g + 0] = a.x; sacc1[4 * g + 1] = a.y;
          sacc1[4 * g + 2] = a.z; sacc1[4 * g + 3] = a.w;
        }
      }

      int pk[8];
#pragma unroll
      for (int i = 0; i < 8; ++i) {
        fh2 h;
        h[0] = (f16)fexp2(sacc[2 * i]);
        h[1] = (f16)fexp2(sacc[2 * i + 1]);
        pk[i] = __builtin_bit_cast(int, h);
      }

      fh8 vfr[2][2];
#pragma unroll
      for (int dt = 0; dt < 2; ++dt)
#pragma unroll
        for (int kb = 0; kb < 2; ++kb)
          vfr[dt][kb] = *(const fh8*)&Vs[c][SWZ(dt * 32 + l31, s * 32 + kb * 16 + hi * 8)];

#pragma unroll
      for (int kb = 0; kb < 2; ++kb) {
        int a01 = pk[4 * kb + 0], a23 = pk[4 * kb + 1];
        int a45 = pk[4 * kb + 2], a67 = pk[4 * kb + 3];
        i4 t;
#if __has_builtin(__builtin_amdgcn_permlane32_swap)
        auto s0 = __builtin_amdgcn_permlane32_swap(a01, a45, false, false);
        auto s1 = __builtin_amdgcn_permlane32_swap(a23, a67, false, false);
        t[0] = s0[0]; t[1] = s1[0]; t[2] = s0[1]; t[3] = s1[1];
#else
        int x01 = __shfl_xor(a01, 32), x23 = __shfl_xor(a23, 32);
        int x45 = __shfl_xor(a45, 32), x67 = __shfl_xor(a67, 32);
        t[0] = hi ? x45 : a01; t[1] = hi ? x67 : a23;
        t[2] = hi ? a45 : x01; t[3] = hi ? a67 : x23;
#endif
        fh8 pf = __builtin_bit_cast(fh8, t);
        lacc = __builtin_amdgcn_mfma_f32_32x32x16_f16(onesf, pf, lacc, 0, 0, 0);
        o_acc[0] = __builtin_amdgcn_mfma_f32_32x32x16_f16(vfr[0][kb], pf, o_acc[0], 0, 0, 0);
        o_acc[1] = __builtin_amdgcn_mfma_f32_32x32x16_f16(vfr[1][kb], pf, o_acc[1], 0, 0, 0);
      }
    };

    half(sacc0, 0, true);
    half(sacc1, 1, false);

    if (kt + 1 < NT) __syncthreads();
  }

  float l = __shfl(lacc[0], l31);
  float inv = 1.0f / l;
  size_t obase = ((size_t)(b * Sq + qrow)) * Eq + hd * 64 + 4 * hi;
#pragma unroll
  for (int dt = 0; dt < 2; ++dt)
#pragma unroll
    for (int g = 0; g < 4; ++g) {
      fh4 o4;
#pragma unroll
      for (int j = 0; j < 4; ++j) o4[j] = (f16)(o_acc[dt][4 * g + j] * inv);
      *(fh4*)&attf[obase + dt * 32 + 8 * g] = o4;
    }
}

// ---------------------------------------------------------------------------
extern "C" void kernel_launch(void* const* d_in, const int* in_sizes, int n_in,
                              void* d_out, int out_size, void* d_ws, size_t ws_size,
                              hipStream_t stream) {
  const float* hs = (const float*)d_in[0];
  const float* rel = (const float*)d_in[1];
  const int* bnd = (const int*)d_in[2];
  const float* wi = (const float*)d_in[3];
  const float* bi = (const float*)d_in[4];
  const float* wo = (const float*)d_in[5];
  const float* bo = (const float*)d_in[6];
  float* out = (float*)d_out;

  const size_t NQ = (size_t)Bsz * Hh * Sq * DHd;  // 8,388,608 (== B*S*E)
  char* p = (char*)d_ws;
  f16* qf = (f16*)p;   p += NQ * 2;
  f16* kf = (f16*)p;   p += NQ * 2;
  f16* vt = (f16*)p;   p += NQ * 2;
  f16* hsf = (f16*)p;  p += NQ * 2;
  f16* attf = (f16*)p; p += NQ * 2;
  f16* wif = (f16*)p;  p += (size_t)3 * Eq * Eq * 2;
  f16* wof = (f16*)p;  p += (size_t)Eq * Eq * 2;
  int* pidr = (int*)p; p += Bsz * Sq * 4;
  float* lfTab = (float*)p;  // Bsz*NCLS*Sq*4 = 327KB
  // total ~93 MB < proven 134 MB footprint

  hipLaunchKernelGGL(pid_kernel, dim3((Bsz * Sq + 255) / 256), dim3(256), 0, stream,
                     bnd, rel, pidr, lfTab);
  hipLaunchKernelGGL(cvt_hs, dim3((int)(NQ / 2048)), dim3(256), 0, stream, hs, hsf);
  hipLaunchKernelGGL(cvt_hs, dim3(3 * Eq * Eq / 2048), dim3(256), 0, stream, wi, wif);
  hipLaunchKernelGGL(cvt_hs, dim3(Eq * Eq / 2048), dim3(256), 0, stream, wo, wof);
  hipLaunchKernelGGL((gemm_f16<1>), dim3(24, 64), dim3(256), 0, stream,
                     hsf, wif, bi, (float*)nullptr, Bsz * Sq, 3 * Eq, Eq,
                     qf, kf, vt);
  hipLaunchKernelGGL(attn_v4, dim3(16, 16, 4), dim3(256), 0, stream,
                     qf, kf, vt, pidr, lfTab, attf);
  hipLaunchKernelGGL((gemm_f16<0>), dim3(8, 64), dim3(256), 0, stream,
                     attf, wof, bo, out, Bsz * Sq, Eq, Eq,
                     nullptr, nullptr, nullptr);
}